// Round 4
// baseline (1993364.648 us; speedup 1.0000x reference)
//
#include <hip/hip_runtime.h>
#include <hip/hip_bf16.h>
#include <stdint.h>

// ResRnn persistent kernel for MI355X — round 4.
// Weight-stationary 2D partition: 8 row-groups x 32 col-blocks = 256 WGs (1/CU).
// Round-3 lesson: DO NOT assume blockIdx->XCD mapping. 160 KiB LDS forces 1 WG/CU, so
// all 256 CUs are filled and each XCD hosts exactly 32 WGs; each WG self-assigns
// g = HW_REG_XCC_ID and c = atomicAdd(per-XCD counter). Group peers are then physically
// co-XCD by construction, so cross-WG exchange is L2-local:
//   - shared-data stores: normal write-back (dirty in the XCD's L2)
//   - shared-data loads:  sc0 (bypass per-CU L1; served coherently by the XCD L2)
//   - group barrier:      plain flag store + sc0 poll loads, all L2-resident
// As-staging uses the transposed conflict-free layout ((i*128+o*16)^((r&7)<<4)).

#define NSTEP  1024
#define BATCH  256
#define INSZ   64
#define SSZ    1024

#define GROUPS 8
#define CBLKS  32
#define RPG    32   // rows per group
#define CPB    32   // cols per block
#define FPAD   16   // flag padding (64 B per flag)

typedef __bf16 bf16x8 __attribute__((ext_vector_type(8)));
typedef float  f32x4  __attribute__((ext_vector_type(4)));

#define SCHED_FENCE() __builtin_amdgcn_sched_barrier(0)

// 8 contiguous 16B loads, L1-bypassing (L2-coherent within the XCD).
__device__ __forceinline__ void issue_stage8(const __bf16* p,
    bf16x8& r0, bf16x8& r1, bf16x8& r2, bf16x8& r3,
    bf16x8& r4, bf16x8& r5, bf16x8& r6, bf16x8& r7)
{
    asm volatile(
        "global_load_dwordx4 %0, %8, off sc0\n\t"
        "global_load_dwordx4 %1, %8, off offset:16 sc0\n\t"
        "global_load_dwordx4 %2, %8, off offset:32 sc0\n\t"
        "global_load_dwordx4 %3, %8, off offset:48 sc0\n\t"
        "global_load_dwordx4 %4, %8, off offset:64 sc0\n\t"
        "global_load_dwordx4 %5, %8, off offset:80 sc0\n\t"
        "global_load_dwordx4 %6, %8, off offset:96 sc0\n\t"
        "global_load_dwordx4 %7, %8, off offset:112 sc0"
        : "=v"(r0), "=v"(r1), "=v"(r2), "=v"(r3),
          "=v"(r4), "=v"(r5), "=v"(r6), "=v"(r7)
        : "v"(p) : "memory");
}

// 4 scattered L1-bypassing dword loads, one latency.
__device__ __forceinline__ void ld_l2_f32x4s(const float* p0, const float* p1,
                                             const float* p2, const float* p3,
                                             float& r0, float& r1, float& r2, float& r3) {
    asm volatile(
        "global_load_dword %0, %4, off sc0\n\t"
        "global_load_dword %1, %5, off sc0\n\t"
        "global_load_dword %2, %6, off sc0\n\t"
        "global_load_dword %3, %7, off sc0\n\t"
        "s_waitcnt vmcnt(0)"
        : "=v"(r0), "=v"(r1), "=v"(r2), "=v"(r3)
        : "v"(p0), "v"(p1), "v"(p2), "v"(p3)
        : "memory");
}

__device__ __forceinline__ unsigned ld_flag(const unsigned* p) {
    unsigned v;
    asm volatile("global_load_dword %0, %1, off sc0\n\ts_waitcnt vmcnt(0)"
                 : "=v"(v) : "v"(p) : "memory");
    return v;
}

// Flag barrier among the 32 WGs of a row-group — entirely within the XCD's L2.
// vmcnt(0)+syncthreads: all waves' write-back stores acked by L2 before the flag
// publishes. Peers poll with sc0 loads. Epochs strictly increasing; signed-diff
// compare tolerates 0xAA poison. ~1 ms bail-out prevents harness-killing hangs.
__device__ __forceinline__ void group_barrier(unsigned* flags, int g, int c,
                                              unsigned e, int tid)
{
    asm volatile("s_waitcnt vmcnt(0)" ::: "memory");
    __syncthreads();
    if (tid == 0)
        flags[(g * CBLKS + c) * FPAD] = e;
    if (tid < 64) {
        const unsigned* fp = &flags[(g * CBLKS + (tid & 31)) * FPAD];
        uint64_t t0 = __builtin_amdgcn_s_memrealtime();
        for (;;) {
            unsigned v = ld_flag(fp);
            if (!__any((int)(v - e) < 0)) break;
            if (__builtin_amdgcn_s_memrealtime() - t0 > 100000ull) break; // ~1ms bail
        }
    }
    __syncthreads();
}

// One K=512 chunk. A read: lane-group kgrp, step kc -> LDS byte
// kgrp*128 + (kc&1)*512 + (((kc>>1)*16) ^ aswz) within the row's 1 KiB.
// cb2 is the WEIGHT chunk byte offset (0 or 1024 within the 2 KiB weight row).
__device__ __forceinline__ void mm_chunk(f32x4* acc, const char* Ab, const char* Bw,
                                         int kbyte, int aswz, int bswz, int cb2)
{
    #pragma unroll
    for (int kc = 0; kc < 16; ++kc) {
        const int aoff = (kc & 1) * 512 + (((kc >> 1) * 16) ^ aswz);
        bf16x8 a = *reinterpret_cast<const bf16x8*>(Ab + aoff);
        bf16x8 w = *reinterpret_cast<const bf16x8*>(Bw + ((cb2 + kc * 64 + kbyte) ^ bswz));
        acc[kc & 3] = __builtin_amdgcn_mfma_f32_16x16x32_bf16(a, w, acc[kc & 3], 0, 0, 0);
    }
}

// Full phase: stage 32x1024 bf16 activation slice (2 chunks) + 32 MFMAs/wave.
// Staging thread (r,o) writes its 8 pieces i at ((i*128 + o*16) ^ ((r&7)<<4)):
// per instruction i, each 8-lane batch (one r, o=0..7) covers 8 distinct 16B slots.
__device__ __forceinline__ void run_phase(const __bf16* ssrc, char* As, int r, int o,
                                          const char* Ab, const char* Bw,
                                          int kbyte, int aswz, int bswz, f32x4* acc)
{
    const int sw = (r & 7) << 4;
    char* const wrow = As + r * 1024;
    bf16x8 a0, a1, a2, a3, a4, a5, a6, a7;

    // chunk 0: k 0..511
    issue_stage8(ssrc, a0, a1, a2, a3, a4, a5, a6, a7);
    asm volatile("s_waitcnt vmcnt(0)" ::: "memory");
    SCHED_FENCE();
    *reinterpret_cast<bf16x8*>(wrow + ((0 * 128 + o * 16) ^ sw)) = a0;
    *reinterpret_cast<bf16x8*>(wrow + ((1 * 128 + o * 16) ^ sw)) = a1;
    *reinterpret_cast<bf16x8*>(wrow + ((2 * 128 + o * 16) ^ sw)) = a2;
    *reinterpret_cast<bf16x8*>(wrow + ((3 * 128 + o * 16) ^ sw)) = a3;
    *reinterpret_cast<bf16x8*>(wrow + ((4 * 128 + o * 16) ^ sw)) = a4;
    *reinterpret_cast<bf16x8*>(wrow + ((5 * 128 + o * 16) ^ sw)) = a5;
    *reinterpret_cast<bf16x8*>(wrow + ((6 * 128 + o * 16) ^ sw)) = a6;
    *reinterpret_cast<bf16x8*>(wrow + ((7 * 128 + o * 16) ^ sw)) = a7;
    __syncthreads();

    // chunk 1 loads fly while chunk 0 computes
    issue_stage8(ssrc + 512, a0, a1, a2, a3, a4, a5, a6, a7);
    mm_chunk(acc, Ab, Bw, kbyte, aswz, bswz, 0);
    __syncthreads();                       // everyone done reading chunk 0
    asm volatile("s_waitcnt vmcnt(0)" ::: "memory");
    SCHED_FENCE();
    *reinterpret_cast<bf16x8*>(wrow + ((0 * 128 + o * 16) ^ sw)) = a0;
    *reinterpret_cast<bf16x8*>(wrow + ((1 * 128 + o * 16) ^ sw)) = a1;
    *reinterpret_cast<bf16x8*>(wrow + ((2 * 128 + o * 16) ^ sw)) = a2;
    *reinterpret_cast<bf16x8*>(wrow + ((3 * 128 + o * 16) ^ sw)) = a3;
    *reinterpret_cast<bf16x8*>(wrow + ((4 * 128 + o * 16) ^ sw)) = a4;
    *reinterpret_cast<bf16x8*>(wrow + ((5 * 128 + o * 16) ^ sw)) = a5;
    *reinterpret_cast<bf16x8*>(wrow + ((6 * 128 + o * 16) ^ sw)) = a6;
    *reinterpret_cast<bf16x8*>(wrow + ((7 * 128 + o * 16) ^ sw)) = a7;
    __syncthreads();
    mm_chunk(acc, Ab, Bw, kbyte, aswz, bswz, 1024);
}

extern "C" __global__ void __launch_bounds__(256, 1)
resrnn_kernel(const float* __restrict__ x,  const float* __restrict__ W1,
              const float* __restrict__ b1, const float* __restrict__ W2,
              const float* __restrict__ b2,
              __bf16* sBuf, __bf16* hBuf, float* sf32, unsigned* flags,
              unsigned* cnt, float* __restrict__ dout)
{
    extern __shared__ char smem[];
    char* W1s = smem;             // 64 KiB: [32 cols][1024 k] bf16, swizzled
    char* W2s = smem + 65536;     // 64 KiB
    char* As  = smem + 131072;    // 32 KiB: staged A chunk [32 rows][512 k] bf16

    const int tid = threadIdx.x;

    // ---- self-assign (g, c): g = physical XCD, c = arrival order within XCD ----
    unsigned xcc;
    asm volatile("s_getreg_b32 %0, hwreg(HW_REG_XCC_ID)" : "=s"(xcc));
    const int g = (int)(xcc & 7);
    if (tid == 0) {
        unsigned cc = atomicAdd(&cnt[g], 1u);
        *reinterpret_cast<volatile unsigned*>(As) = cc;
    }
    __syncthreads();
    const int c = (int)(*reinterpret_cast<volatile unsigned*>(As) & 31u);
    __syncthreads();

    const int rb = g * RPG;
    const int cb = c * CPB;

    // ---- stage weight slices to LDS (fp32 -> bf16, XOR-swizzle by col) ----
    {
        const int lc  = tid >> 3;
        const int seg = (tid & 7) * 128;
        const int sw  = (lc & 7) << 4;
        const float* w1p = W1 + (size_t)(cb + lc) * SSZ + seg;
        const float* w2p = W2 + (size_t)(cb + lc) * SSZ + seg;
        char* d1 = W1s + lc * 2048;
        char* d2 = W2s + lc * 2048;
        #pragma unroll 4
        for (int kk = 0; kk < 16; ++kk) {
            const int kb = (seg + kk * 8) * 2;
            float4 f0 = reinterpret_cast<const float4*>(w1p)[kk * 2 + 0];
            float4 f1 = reinterpret_cast<const float4*>(w1p)[kk * 2 + 1];
            bf16x8 v;
            v[0] = (__bf16)f0.x; v[1] = (__bf16)f0.y; v[2] = (__bf16)f0.z; v[3] = (__bf16)f0.w;
            v[4] = (__bf16)f1.x; v[5] = (__bf16)f1.y; v[6] = (__bf16)f1.z; v[7] = (__bf16)f1.w;
            *reinterpret_cast<bf16x8*>(d1 + (kb ^ sw)) = v;
            f0 = reinterpret_cast<const float4*>(w2p)[kk * 2 + 0];
            f1 = reinterpret_cast<const float4*>(w2p)[kk * 2 + 1];
            v[0] = (__bf16)f0.x; v[1] = (__bf16)f0.y; v[2] = (__bf16)f0.z; v[3] = (__bf16)f0.w;
            v[4] = (__bf16)f1.x; v[5] = (__bf16)f1.y; v[6] = (__bf16)f1.z; v[7] = (__bf16)f1.w;
            *reinterpret_cast<bf16x8*>(d2 + (kb ^ sw)) = v;
        }
    }

    // ---- init our tile: sBuf = [x_0 | 0] (bf16), sf32[buf0] = 0 (plain stores) ----
    {
        const int e0  = tid * 4;
        const int row = rb + (e0 >> 5);
        const int col = cb + (e0 & 31);
        float4 z4 = {0.f, 0.f, 0.f, 0.f};
        *reinterpret_cast<float4*>(sf32 + (size_t)row * SSZ + col) = z4;
        __bf16* sp = sBuf + (size_t)row * SSZ + col;
        if (c < 2) {
            const float* xp = x + (size_t)row * INSZ + col;
            sp[0] = (__bf16)xp[0]; sp[1] = (__bf16)xp[1];
            sp[2] = (__bf16)xp[2]; sp[3] = (__bf16)xp[3];
        } else {
            sp[0] = (__bf16)0.f; sp[1] = (__bf16)0.f;
            sp[2] = (__bf16)0.f; sp[3] = (__bf16)0.f;
        }
    }

    group_barrier(flags, g, c, 1u, tid);

    // ---- per-thread geometry ----
    const int lane  = tid & 63;
    const int wv    = tid >> 6;
    const int mh    = wv >> 1;                       // row half
    const int nh    = wv & 1;                        // col half
    const int kgrp  = lane >> 4;
    const int kbyte = kgrp * 16;
    const int aloc  = mh * 16 + (lane & 15);         // A row within group slice
    const int aswz  = (aloc & 7) << 4;
    const char* Ab  = As + aloc * 1024 + kgrp * 128; // A read base (transposed layout)
    const int lc    = nh * 16 + (lane & 15);         // local col 0..31
    const int bswz  = (lc & 7) << 4;
    const char* Bw1 = W1s + lc * 2048;
    const char* Bw2 = W2s + lc * 2048;
    const float bias1 = b1[cb + lc];
    const float bias2 = b2[cb + lc];
    const int drow0 = rb + mh * 16 + kgrp * 4;       // C/D row base
    const int dcol  = cb + lc;                       // C/D col
    const float P = 0.97f, OMP = 1.0f - 0.97f;

    // staging role: thread covers row r (of 32), octant o (64 k-elems)
    const int r = tid >> 3;
    const int o = tid & 7;
    const __bf16* pS = sBuf + (size_t)(rb + r) * SSZ + o * 64;
    const __bf16* pH = hBuf + (size_t)(rb + r) * SSZ + o * 64;

    for (int t = 0; t < NSTEP; ++t) {
        // ---- phase 1: h = |s @ W1^T + b1| ----
        f32x4 acc[4];
        #pragma unroll
        for (int i = 0; i < 4; ++i) acc[i] = (f32x4){0.f, 0.f, 0.f, 0.f};
        run_phase(pS, As, r, o, Ab, Bw1, kbyte, aswz, bswz, acc);
        f32x4 h4 = (acc[0] + acc[1]) + (acc[2] + acc[3]);
        #pragma unroll
        for (int j = 0; j < 4; ++j) {
            float hv = fabsf(h4[j] + bias1);
            hBuf[(size_t)(drow0 + j) * SSZ + dcol] = (__bf16)hv;   // write-back L2
        }
        group_barrier(flags, g, c, (unsigned)(2 + 2 * t), tid);

        // ---- phase 2: S' = p*s + (1-p)*(h @ W2^T + b2) ----
        #pragma unroll
        for (int i = 0; i < 4; ++i) acc[i] = (f32x4){0.f, 0.f, 0.f, 0.f};
        run_phase(pH, As, r, o, Ab, Bw2, kbyte, aswz, bswz, acc);
        f32x4 u4 = (acc[0] + acc[1]) + (acc[2] + acc[3]);

        const float* srd = sf32 + (size_t)(t & 1) * (BATCH * SSZ);
        float*       swr = sf32 + (size_t)((t + 1) & 1) * (BATCH * SSZ);
        float sp[4];
        if (c < 2) {  // shifted-in x_t columns: exact fp32 from input (read-only)
            const float* xp = x + (size_t)t * (BATCH * INSZ);
            #pragma unroll
            for (int j = 0; j < 4; ++j) sp[j] = xp[(size_t)(drow0 + j) * INSZ + dcol];
        } else {      // fp32 master from WG(g,c-2), via XCD L2
            ld_l2_f32x4s(&srd[(size_t)(drow0 + 0) * SSZ + (dcol - 64)],
                         &srd[(size_t)(drow0 + 1) * SSZ + (dcol - 64)],
                         &srd[(size_t)(drow0 + 2) * SSZ + (dcol - 64)],
                         &srd[(size_t)(drow0 + 3) * SSZ + (dcol - 64)],
                         sp[0], sp[1], sp[2], sp[3]);
        }
        #pragma unroll
        for (int j = 0; j < 4; ++j) {
            const int row = drow0 + j;
            const float snew = P * sp[j] + OMP * (u4[j] + bias2);
            swr[(size_t)row * SSZ + dcol] = snew;                  // fp32 master
            if (c < 30)                                            // shifted bf16 publish
                sBuf[(size_t)row * SSZ + (dcol + 64)] = (__bf16)snew;
            else if (t == NSTEP - 1)                               // final output cols
                dout[row * 64 + (dcol - 960)] = snew;
        }
        if (c < 2 && t < NSTEP - 1) {  // blocks 0,1 of s_{t+1} = x_{t+1}
            #pragma unroll
            for (int j = 0; j < 4; ++j) {
                const int row = drow0 + j;
                sBuf[(size_t)row * SSZ + dcol] =
                    (__bf16)x[(size_t)(t + 1) * (BATCH * INSZ) + (size_t)row * INSZ + dcol];
            }
        }
        if (t < NSTEP - 1)
            group_barrier(flags, g, c, (unsigned)(3 + 2 * t), tid);
    }
}

extern "C" void kernel_launch(void* const* d_in, const int* in_sizes, int n_in,
                              void* d_out, int out_size, void* d_ws, size_t ws_size,
                              hipStream_t stream)
{
    const float* x  = (const float*)d_in[0];
    const float* W1 = (const float*)d_in[1];
    const float* b1 = (const float*)d_in[2];
    const float* W2 = (const float*)d_in[3];
    const float* b2 = (const float*)d_in[4];
    float* dout = (float*)d_out;

    char* ws = (char*)d_ws;
    __bf16*   sBuf  = (__bf16*)(ws);                        // 512 KiB: shifted s_t, bf16
    __bf16*   hBuf  = (__bf16*)(ws + (512 << 10));          // 512 KiB: h, bf16
    float*    sf32  = (float*)(ws + (1 << 20));             // 2 MiB: fp32 S ping-pong
    unsigned* flags = (unsigned*)(ws + (3 << 20));          // 16 KiB: padded flags
    unsigned* cnt   = (unsigned*)(ws + (3 << 20) + 16384);  // 32 B: per-XCD counters

    (void)in_sizes; (void)n_in; (void)out_size; (void)ws_size;

    hipMemsetAsync(cnt, 0, 8 * sizeof(unsigned), stream);   // captured as a graph node

    hipFuncSetAttribute(reinterpret_cast<const void*>(&resrnn_kernel),
                        hipFuncAttributeMaxDynamicSharedMemorySize, 163840);
    hipLaunchKernelGGL(resrnn_kernel, dim3(256), dim3(256), 163840, stream,
                       x, W1, b1, W2, b2, sBuf, hBuf, sf32, flags, cnt, dout);
}

// Round 5
// 11412.347 us; speedup vs baseline: 174.6674x; 174.6674x over previous
//
#include <hip/hip_runtime.h>
#include <hip/hip_bf16.h>
#include <stdint.h>

// ResRnn persistent kernel for MI355X — round 5.
// Weight-stationary 2D partition: 8 row-groups x 32 col-blocks = 256 WGs (1/CU);
// W1/W2 32x1024 bf16 slices LDS-resident (128 KiB), XOR-swizzled.
// Coherence protocol = round 2's PROVEN one (memory-side / Infinity-Cache):
//   - shared-data stores: sc0 sc1 write-through (never dirty in a private L2)
//   - shared-data loads:  sc0 sc1 (L3-coherent)
//   - group barrier:      relaxed agent-scope HIP atomics (store + poll)
// Round-4 lesson: sc0-only XCD-local coherence is NOT timely on gfx950 (every
// barrier hit its bail-out; 2 s run). Don't bet on unproven cache semantics.
// Round-2 lesson: LDS A-staging caused 2.4e9 bank conflicts + 4 extra syncs/step.
// This round drops A-staging: per-lane A-fragments load DIRECTLY from L3 with a
// 2-deep 8-load register pipeline (vmcnt(8) + sched_barrier per guide rule #18).
// sprev is prefetched before the mid barrier so its latency hides under the poll.

#define NSTEP  1024
#define BATCH  256
#define INSZ   64
#define SSZ    1024

#define GROUPS 8
#define CBLKS  32
#define RPG    32   // rows per group
#define CPB    32   // cols per block
#define FPAD   16   // flag padding (64 B per flag)

typedef __bf16 bf16x8 __attribute__((ext_vector_type(8)));
typedef float  f32x4  __attribute__((ext_vector_type(4)));

#define SCHED_FENCE() __builtin_amdgcn_sched_barrier(0)
// rule #18: sched_barrier right after an inline-asm waitcnt, else MFMA hoists past it
#define WAITV8() do { asm volatile("s_waitcnt vmcnt(8)" ::: "memory"); SCHED_FENCE(); } while (0)
#define WAITV0() do { asm volatile("s_waitcnt vmcnt(0)" ::: "memory"); SCHED_FENCE(); } while (0)

// 8 A-fragment loads (16B each, stride 64B = one MFMA k-step), L3-coherent.
// =&v early-clobber: outputs must not alias the address pair while loads issue.
__device__ __forceinline__ void issue8(const char* p,
    bf16x8& r0, bf16x8& r1, bf16x8& r2, bf16x8& r3,
    bf16x8& r4, bf16x8& r5, bf16x8& r6, bf16x8& r7)
{
    asm volatile(
        "global_load_dwordx4 %0, %8, off sc0 sc1\n\t"
        "global_load_dwordx4 %1, %8, off offset:64 sc0 sc1\n\t"
        "global_load_dwordx4 %2, %8, off offset:128 sc0 sc1\n\t"
        "global_load_dwordx4 %3, %8, off offset:192 sc0 sc1\n\t"
        "global_load_dwordx4 %4, %8, off offset:256 sc0 sc1\n\t"
        "global_load_dwordx4 %5, %8, off offset:320 sc0 sc1\n\t"
        "global_load_dwordx4 %6, %8, off offset:384 sc0 sc1\n\t"
        "global_load_dwordx4 %7, %8, off offset:448 sc0 sc1"
        : "=&v"(r0), "=&v"(r1), "=&v"(r2), "=&v"(r3),
          "=&v"(r4), "=&v"(r5), "=&v"(r6), "=&v"(r7)
        : "v"(p) : "memory");
}

// Issue-only prefetch of 4 scattered coherent dwords (completion guaranteed by a
// later vmcnt(0) — here, the barrier entry drain).
__device__ __forceinline__ void issue4f(const float* p0, const float* p1,
                                        const float* p2, const float* p3,
                                        float& r0, float& r1, float& r2, float& r3)
{
    asm volatile(
        "global_load_dword %0, %4, off sc0 sc1\n\t"
        "global_load_dword %1, %5, off sc0 sc1\n\t"
        "global_load_dword %2, %6, off sc0 sc1\n\t"
        "global_load_dword %3, %7, off sc0 sc1"
        : "=&v"(r0), "=&v"(r1), "=&v"(r2), "=&v"(r3)
        : "v"(p0), "v"(p1), "v"(p2), "v"(p3)
        : "memory");
}

__device__ __forceinline__ void st_coh_u16(void* p, unsigned short v) {
    asm volatile("global_store_short %0, %1, off sc0 sc1" :: "v"(p), "v"(v) : "memory");
}
__device__ __forceinline__ void st_coh_f32(void* p, float v) {
    asm volatile("global_store_dword %0, %1, off sc0 sc1" :: "v"(p), "v"(v) : "memory");
}

// Flag barrier among the 32 WGs of a row-group (round-2 proven form).
// vmcnt(0)+syncthreads: all write-through stores are at the coherence point before
// the flag publishes. Epochs strictly increasing; signed diff tolerates 0xAA poison.
__device__ __forceinline__ void group_barrier(unsigned* flags, int g, int c,
                                              unsigned e, int tid)
{
    asm volatile("s_waitcnt vmcnt(0)" ::: "memory");
    __syncthreads();
    if (tid == 0)
        __hip_atomic_store(&flags[(g * CBLKS + c) * FPAD], e, __ATOMIC_RELAXED,
                           __HIP_MEMORY_SCOPE_AGENT);
    if (tid < 64) {
        uint64_t t0 = __builtin_amdgcn_s_memrealtime();
        for (;;) {
            unsigned v = e;
            if (tid < CBLKS)
                v = __hip_atomic_load(&flags[(g * CBLKS + tid) * FPAD], __ATOMIC_RELAXED,
                                      __HIP_MEMORY_SCOPE_AGENT);
            if (!__any((int)(v - e) < 0)) break;
            if (__builtin_amdgcn_s_memrealtime() - t0 > 400000ull) break; // ~4ms bail
        }
    }
    __syncthreads();
}

// 8 MFMAs for k-steps BASE..BASE+7; A from the given register block, B from LDS.
#define MFMA8(BASE, A0, A1, A2, A3, A4, A5, A6, A7)                                        \
    do {                                                                                   \
        acc0 = __builtin_amdgcn_mfma_f32_16x16x32_bf16(A0,                                 \
            *reinterpret_cast<const bf16x8*>(Bw + ((((BASE) + 0) * 64 + kbyte) ^ bswz)),   \
            acc0, 0, 0, 0);                                                                \
        acc1 = __builtin_amdgcn_mfma_f32_16x16x32_bf16(A1,                                 \
            *reinterpret_cast<const bf16x8*>(Bw + ((((BASE) + 1) * 64 + kbyte) ^ bswz)),   \
            acc1, 0, 0, 0);                                                                \
        acc2 = __builtin_amdgcn_mfma_f32_16x16x32_bf16(A2,                                 \
            *reinterpret_cast<const bf16x8*>(Bw + ((((BASE) + 2) * 64 + kbyte) ^ bswz)),   \
            acc2, 0, 0, 0);                                                                \
        acc3 = __builtin_amdgcn_mfma_f32_16x16x32_bf16(A3,                                 \
            *reinterpret_cast<const bf16x8*>(Bw + ((((BASE) + 3) * 64 + kbyte) ^ bswz)),   \
            acc3, 0, 0, 0);                                                                \
        acc0 = __builtin_amdgcn_mfma_f32_16x16x32_bf16(A4,                                 \
            *reinterpret_cast<const bf16x8*>(Bw + ((((BASE) + 4) * 64 + kbyte) ^ bswz)),   \
            acc0, 0, 0, 0);                                                                \
        acc1 = __builtin_amdgcn_mfma_f32_16x16x32_bf16(A5,                                 \
            *reinterpret_cast<const bf16x8*>(Bw + ((((BASE) + 5) * 64 + kbyte) ^ bswz)),   \
            acc1, 0, 0, 0);                                                                \
        acc2 = __builtin_amdgcn_mfma_f32_16x16x32_bf16(A6,                                 \
            *reinterpret_cast<const bf16x8*>(Bw + ((((BASE) + 6) * 64 + kbyte) ^ bswz)),   \
            acc2, 0, 0, 0);                                                                \
        acc3 = __builtin_amdgcn_mfma_f32_16x16x32_bf16(A7,                                 \
            *reinterpret_cast<const bf16x8*>(Bw + ((((BASE) + 7) * 64 + kbyte) ^ bswz)),   \
            acc3, 0, 0, 0);                                                                \
    } while (0)

// One 16x16 tile over K=1024: 32 direct-from-L3 A loads (4 blocks of 8) in a 2-deep
// X/Y register pipeline; B from swizzled LDS weights. Sequence per block: wait the
// oldest block (vmcnt(8)), consume it (8 MFMA), reuse its registers for block+2.
__device__ __forceinline__ f32x4 phase_mm(const char* Ab, const char* Bw,
                                          int kbyte, int bswz)
{
    f32x4 acc0 = {0.f, 0.f, 0.f, 0.f}, acc1 = acc0, acc2 = acc0, acc3 = acc0;
    bf16x8 x0, x1, x2, x3, x4, x5, x6, x7;
    bf16x8 y0, y1, y2, y3, y4, y5, y6, y7;

    issue8(Ab,        x0, x1, x2, x3, x4, x5, x6, x7);
    issue8(Ab +  512, y0, y1, y2, y3, y4, y5, y6, y7);
    WAITV8();                                       // block 0 (X) complete
    MFMA8(0,  x0, x1, x2, x3, x4, x5, x6, x7);
    issue8(Ab + 1024, x0, x1, x2, x3, x4, x5, x6, x7);
    WAITV8();                                       // block 1 (Y) complete
    MFMA8(8,  y0, y1, y2, y3, y4, y5, y6, y7);
    issue8(Ab + 1536, y0, y1, y2, y3, y4, y5, y6, y7);
    WAITV8();                                       // block 2 (X) complete
    MFMA8(16, x0, x1, x2, x3, x4, x5, x6, x7);
    WAITV0();                                       // block 3 (Y) complete
    MFMA8(24, y0, y1, y2, y3, y4, y5, y6, y7);

    return (acc0 + acc1) + (acc2 + acc3);
}

extern "C" __global__ void __launch_bounds__(256, 1)
resrnn_kernel(const float* __restrict__ x,  const float* __restrict__ W1,
              const float* __restrict__ b1, const float* __restrict__ W2,
              const float* __restrict__ b2,
              __bf16* sBuf, __bf16* hBuf, float* sf32, unsigned* flags,
              float* __restrict__ dout)
{
    extern __shared__ char smem[];
    char* W1s = smem;             // 64 KiB: [32 cols][1024 k] bf16, swizzled
    char* W2s = smem + 65536;     // 64 KiB

    const int tid = threadIdx.x;
    const int bid = blockIdx.x;
    const int g   = bid & 7;      // row group
    const int c   = bid >> 3;     // col block
    const int rb  = g * RPG;
    const int cb  = c * CPB;

    // ---- stage weight slices to LDS (fp32 -> bf16, XOR-swizzle by col) ----
    {
        const int lc  = tid >> 3;
        const int seg = (tid & 7) * 128;
        const int sw  = (lc & 7) << 4;
        const float* w1p = W1 + (size_t)(cb + lc) * SSZ + seg;
        const float* w2p = W2 + (size_t)(cb + lc) * SSZ + seg;
        char* d1 = W1s + lc * 2048;
        char* d2 = W2s + lc * 2048;
        #pragma unroll 4
        for (int kk = 0; kk < 16; ++kk) {
            const int kb = (seg + kk * 8) * 2;
            float4 f0 = reinterpret_cast<const float4*>(w1p)[kk * 2 + 0];
            float4 f1 = reinterpret_cast<const float4*>(w1p)[kk * 2 + 1];
            bf16x8 v;
            v[0] = (__bf16)f0.x; v[1] = (__bf16)f0.y; v[2] = (__bf16)f0.z; v[3] = (__bf16)f0.w;
            v[4] = (__bf16)f1.x; v[5] = (__bf16)f1.y; v[6] = (__bf16)f1.z; v[7] = (__bf16)f1.w;
            *reinterpret_cast<bf16x8*>(d1 + (kb ^ sw)) = v;
            f0 = reinterpret_cast<const float4*>(w2p)[kk * 2 + 0];
            f1 = reinterpret_cast<const float4*>(w2p)[kk * 2 + 1];
            v[0] = (__bf16)f0.x; v[1] = (__bf16)f0.y; v[2] = (__bf16)f0.z; v[3] = (__bf16)f0.w;
            v[4] = (__bf16)f1.x; v[5] = (__bf16)f1.y; v[6] = (__bf16)f1.z; v[7] = (__bf16)f1.w;
            *reinterpret_cast<bf16x8*>(d2 + (kb ^ sw)) = v;
        }
    }

    // ---- init our tile: sBuf = [x_0 | 0] (bf16), sf32[buf0] = 0, coherent stores ----
    {
        const int e0  = tid * 4;
        const int row = rb + (e0 >> 5);
        const int col = cb + (e0 & 31);
        float* sp32 = sf32 + (size_t)row * SSZ + col;
        st_coh_f32(sp32 + 0, 0.f); st_coh_f32(sp32 + 1, 0.f);
        st_coh_f32(sp32 + 2, 0.f); st_coh_f32(sp32 + 3, 0.f);
        __bf16* sp = sBuf + (size_t)row * SSZ + col;
        if (c < 2) {
            const float* xp = x + (size_t)row * INSZ + col;
            #pragma unroll
            for (int i = 0; i < 4; ++i)
                st_coh_u16(sp + i, __builtin_bit_cast(unsigned short, (__bf16)xp[i]));
        } else {
            #pragma unroll
            for (int i = 0; i < 4; ++i)
                st_coh_u16(sp + i, __builtin_bit_cast(unsigned short, (__bf16)0.f));
        }
    }

    group_barrier(flags, g, c, 1u, tid);

    // ---- per-thread geometry ----
    const int lane  = tid & 63;
    const int wv    = tid >> 6;
    const int mh    = wv >> 1;                       // row half
    const int nh    = wv & 1;                        // col half
    const int kgrp  = lane >> 4;
    const int kbyte = kgrp * 16;
    const int arow  = rb + mh * 16 + (lane & 15);    // A operand row (global)
    const char* AbS = (const char*)sBuf + (size_t)arow * 2048 + kgrp * 16;
    const char* AbH = (const char*)hBuf + (size_t)arow * 2048 + kgrp * 16;
    const int lc    = nh * 16 + (lane & 15);         // local col 0..31
    const int bswz  = (lc & 7) << 4;
    const char* Bw1 = W1s + lc * 2048;
    const char* Bw2 = W2s + lc * 2048;
    const float bias1 = b1[cb + lc];
    const float bias2 = b2[cb + lc];
    const int drow0 = rb + mh * 16 + kgrp * 4;       // C/D row base
    const int dcol  = cb + lc;                       // C/D col
    const float P = 0.97f, OMP = 1.0f - 0.97f;

    for (int t = 0; t < NSTEP; ++t) {
        // ---- phase 1: h = |s @ W1^T + b1| (A direct from L3, pipelined) ----
        {
            const char* Bw = Bw1;
            f32x4 h4 = phase_mm(AbS, Bw, kbyte, bswz);
            #pragma unroll
            for (int j = 0; j < 4; ++j) {
                float hv = fabsf(h4[j] + bias1);
                st_coh_u16(hBuf + (size_t)(drow0 + j) * SSZ + dcol,
                           __builtin_bit_cast(unsigned short, (__bf16)hv));
            }
        }

        // ---- prefetch sprev (needed after phase 2); latency hides under barrier ----
        const float* srd = sf32 + (size_t)(t & 1) * (BATCH * SSZ);
        float sp0, sp1, sp2, sp3;
        if (c < 2) {  // shifted-in x_t columns: exact fp32 from read-only input
            const float* xp = x + (size_t)t * (BATCH * INSZ);
            sp0 = xp[(size_t)(drow0 + 0) * INSZ + dcol];
            sp1 = xp[(size_t)(drow0 + 1) * INSZ + dcol];
            sp2 = xp[(size_t)(drow0 + 2) * INSZ + dcol];
            sp3 = xp[(size_t)(drow0 + 3) * INSZ + dcol];
        } else {      // fp32 master written by WG(g,c-2) last step (safe since last barrier)
            issue4f(&srd[(size_t)(drow0 + 0) * SSZ + (dcol - 64)],
                    &srd[(size_t)(drow0 + 1) * SSZ + (dcol - 64)],
                    &srd[(size_t)(drow0 + 2) * SSZ + (dcol - 64)],
                    &srd[(size_t)(drow0 + 3) * SSZ + (dcol - 64)],
                    sp0, sp1, sp2, sp3);    // completed by barrier-entry vmcnt(0)
        }

        group_barrier(flags, g, c, (unsigned)(2 + 2 * t), tid);

        // ---- phase 2: S' = p*s + (1-p)*(h @ W2^T + b2) ----
        f32x4 u4 = phase_mm(AbH, Bw2, kbyte, bswz);

        float*  swr = sf32 + (size_t)((t + 1) & 1) * (BATCH * SSZ);
        float spv[4] = {sp0, sp1, sp2, sp3};
        #pragma unroll
        for (int j = 0; j < 4; ++j) {
            const int row = drow0 + j;
            const float snew = P * spv[j] + OMP * (u4[j] + bias2);
            st_coh_f32(&swr[(size_t)row * SSZ + dcol], snew);       // fp32 master
            if (c < 30)                                             // shifted bf16 publish
                st_coh_u16(sBuf + (size_t)row * SSZ + (dcol + 64),
                           __builtin_bit_cast(unsigned short, (__bf16)snew));
            else if (t == NSTEP - 1)                                // final output cols
                dout[row * 64 + (dcol - 960)] = snew;
        }
        if (c < 2 && t < NSTEP - 1) {  // blocks 0,1 of s_{t+1} = x_{t+1}
            #pragma unroll
            for (int j = 0; j < 4; ++j) {
                const int row = drow0 + j;
                st_coh_u16(sBuf + (size_t)row * SSZ + dcol,
                           __builtin_bit_cast(unsigned short,
                               (__bf16)x[(size_t)(t + 1) * (BATCH * INSZ) +
                                         (size_t)row * INSZ + dcol]));
            }
        }
        if (t < NSTEP - 1)
            group_barrier(flags, g, c, (unsigned)(3 + 2 * t), tid);
    }
}

extern "C" void kernel_launch(void* const* d_in, const int* in_sizes, int n_in,
                              void* d_out, int out_size, void* d_ws, size_t ws_size,
                              hipStream_t stream)
{
    const float* x  = (const float*)d_in[0];
    const float* W1 = (const float*)d_in[1];
    const float* b1 = (const float*)d_in[2];
    const float* W2 = (const float*)d_in[3];
    const float* b2 = (const float*)d_in[4];
    float* dout = (float*)d_out;

    char* ws = (char*)d_ws;
    __bf16*   sBuf  = (__bf16*)(ws);                 // 512 KiB: shifted s_t, bf16
    __bf16*   hBuf  = (__bf16*)(ws + (512 << 10));   // 512 KiB: h, bf16
    float*    sf32  = (float*)(ws + (1 << 20));      // 2 MiB: fp32 S ping-pong
    unsigned* flags = (unsigned*)(ws + (3 << 20));   // 16 KiB: padded flags

    (void)in_sizes; (void)n_in; (void)out_size; (void)ws_size;

    hipFuncSetAttribute(reinterpret_cast<const void*>(&resrnn_kernel),
                        hipFuncAttributeMaxDynamicSharedMemorySize, 131072);
    hipLaunchKernelGGL(resrnn_kernel, dim3(256), dim3(256), 131072, stream,
                       x, W1, b1, W2, b2, sBuf, hBuf, sf32, flags, dout);
}

// Round 7
// 10902.271 us; speedup vs baseline: 182.8394x; 1.0468x over previous
//
#include <hip/hip_runtime.h>
#include <hip/hip_bf16.h>
#include <stdint.h>

// ResRnn persistent kernel for MI355X — round 7 (round 6 fixed: inline-asm operands
// must be ext_vector types, not HIP struct vectors like float4/uint2).
// Weight-stationary 2D partition: 8 row-groups x 32 col-blocks = 256 WGs (1/CU);
// W1/W2 32x1024 bf16 slices LDS-resident (128 KiB), XOR-swizzled. Coherence = round-2/5
// proven protocol: sc0 sc1 write-through stores, sc0 sc1 loads, relaxed agent atomics
// for flags. Round-5 analysis: ~10 of 12.3 us/step is the two exchange round trips; the
// scattered 2B/4B write-through stores force memory-side read-modify-write (FETCH_SIZE
// 1.1 GB ~= line footprint of writes), stretching the pre-flag vmcnt(0) drain.
// Changes vs round 5:
//  1) Full-line publication: result tiles transpose through a padded LDS scratch; the
//     store pass emits row-contiguous 64B-aligned lines (no RMW).
//  2) phase_mm issues all 32 A-loads upfront, drains vmcnt(24/16/8/0): one exposed L3
//     latency per phase.

#define NSTEP  1024
#define BATCH  256
#define INSZ   64
#define SSZ    1024

#define GROUPS 8
#define CBLKS  32
#define RPG    32   // rows per group
#define CPB    32   // cols per block
#define FPAD   16   // flag padding (64 B per flag)
#define TSTR   36   // transpose-tile row stride in f32 (16B-aligned, bank-spread)

typedef __bf16  bf16x8 __attribute__((ext_vector_type(8)));
typedef float   f32x4  __attribute__((ext_vector_type(4)));
typedef unsigned u32x2 __attribute__((ext_vector_type(2)));

#define SCHED_FENCE() __builtin_amdgcn_sched_barrier(0)
// rule #18: sched_barrier right after an inline-asm waitcnt, else MFMA hoists past it
#define WAITN(n) do { asm volatile("s_waitcnt vmcnt(" #n ")" ::: "memory"); SCHED_FENCE(); } while (0)

// 8 A-fragment loads (16B each, stride 64B = one MFMA k-step), L3-coherent.
__device__ __forceinline__ void issue8(const char* p,
    bf16x8& r0, bf16x8& r1, bf16x8& r2, bf16x8& r3,
    bf16x8& r4, bf16x8& r5, bf16x8& r6, bf16x8& r7)
{
    asm volatile(
        "global_load_dwordx4 %0, %8, off sc0 sc1\n\t"
        "global_load_dwordx4 %1, %8, off offset:64 sc0 sc1\n\t"
        "global_load_dwordx4 %2, %8, off offset:128 sc0 sc1\n\t"
        "global_load_dwordx4 %3, %8, off offset:192 sc0 sc1\n\t"
        "global_load_dwordx4 %4, %8, off offset:256 sc0 sc1\n\t"
        "global_load_dwordx4 %5, %8, off offset:320 sc0 sc1\n\t"
        "global_load_dwordx4 %6, %8, off offset:384 sc0 sc1\n\t"
        "global_load_dwordx4 %7, %8, off offset:448 sc0 sc1"
        : "=&v"(r0), "=&v"(r1), "=&v"(r2), "=&v"(r3),
          "=&v"(r4), "=&v"(r5), "=&v"(r6), "=&v"(r7)
        : "v"(p) : "memory");
}

// Issue-only prefetch of 4 scattered coherent dwords (completed by the next vmcnt(0),
// i.e. the barrier-entry drain).
__device__ __forceinline__ void issue4f(const float* p0, const float* p1,
                                        const float* p2, const float* p3,
                                        float& r0, float& r1, float& r2, float& r3)
{
    asm volatile(
        "global_load_dword %0, %4, off sc0 sc1\n\t"
        "global_load_dword %1, %5, off sc0 sc1\n\t"
        "global_load_dword %2, %6, off sc0 sc1\n\t"
        "global_load_dword %3, %7, off sc0 sc1"
        : "=&v"(r0), "=&v"(r1), "=&v"(r2), "=&v"(r3)
        : "v"(p0), "v"(p1), "v"(p2), "v"(p3)
        : "memory");
}

__device__ __forceinline__ void st_coh_u16(void* p, unsigned short v) {
    asm volatile("global_store_short %0, %1, off sc0 sc1" :: "v"(p), "v"(v) : "memory");
}
__device__ __forceinline__ void st_coh_f32(void* p, float v) {
    asm volatile("global_store_dword %0, %1, off sc0 sc1" :: "v"(p), "v"(v) : "memory");
}
__device__ __forceinline__ void st_coh_b64(void* p, u32x2 v) {
    asm volatile("global_store_dwordx2 %0, %1, off sc0 sc1" :: "v"(p), "v"(v) : "memory");
}
__device__ __forceinline__ void st_coh_b128(void* p, f32x4 v) {
    asm volatile("global_store_dwordx4 %0, %1, off sc0 sc1" :: "v"(p), "v"(v) : "memory");
}

__device__ __forceinline__ u32x2 pack_bf16x4(f32x4 f) {
    unsigned a = __builtin_bit_cast(unsigned short, (__bf16)f[0]);
    unsigned b = __builtin_bit_cast(unsigned short, (__bf16)f[1]);
    unsigned c = __builtin_bit_cast(unsigned short, (__bf16)f[2]);
    unsigned d = __builtin_bit_cast(unsigned short, (__bf16)f[3]);
    u32x2 r; r[0] = a | (b << 16); r[1] = c | (d << 16);
    return r;
}

// Flag barrier among the 32 WGs of a row-group (round-2/5 proven form).
__device__ __forceinline__ void group_barrier(unsigned* flags, int g, int c,
                                              unsigned e, int tid)
{
    asm volatile("s_waitcnt vmcnt(0)" ::: "memory");
    __syncthreads();
    if (tid == 0)
        __hip_atomic_store(&flags[(g * CBLKS + c) * FPAD], e, __ATOMIC_RELAXED,
                           __HIP_MEMORY_SCOPE_AGENT);
    if (tid < 64) {
        uint64_t t0 = __builtin_amdgcn_s_memrealtime();
        for (;;) {
            unsigned v = e;
            if (tid < CBLKS)
                v = __hip_atomic_load(&flags[(g * CBLKS + tid) * FPAD], __ATOMIC_RELAXED,
                                      __HIP_MEMORY_SCOPE_AGENT);
            if (!__any((int)(v - e) < 0)) break;
            if (__builtin_amdgcn_s_memrealtime() - t0 > 400000ull) break; // ~4ms bail
        }
    }
    __syncthreads();
}

// 8 MFMAs for k-steps BASE..BASE+7; A from registers, B from swizzled LDS weights.
#define MFMA8(BASE, A0, A1, A2, A3, A4, A5, A6, A7)                                        \
    do {                                                                                   \
        acc0 = __builtin_amdgcn_mfma_f32_16x16x32_bf16(A0,                                 \
            *reinterpret_cast<const bf16x8*>(Bw + ((((BASE) + 0) * 64 + kbyte) ^ bswz)),   \
            acc0, 0, 0, 0);                                                                \
        acc1 = __builtin_amdgcn_mfma_f32_16x16x32_bf16(A1,                                 \
            *reinterpret_cast<const bf16x8*>(Bw + ((((BASE) + 1) * 64 + kbyte) ^ bswz)),   \
            acc1, 0, 0, 0);                                                                \
        acc2 = __builtin_amdgcn_mfma_f32_16x16x32_bf16(A2,                                 \
            *reinterpret_cast<const bf16x8*>(Bw + ((((BASE) + 2) * 64 + kbyte) ^ bswz)),   \
            acc2, 0, 0, 0);                                                                \
        acc3 = __builtin_amdgcn_mfma_f32_16x16x32_bf16(A3,                                 \
            *reinterpret_cast<const bf16x8*>(Bw + ((((BASE) + 3) * 64 + kbyte) ^ bswz)),   \
            acc3, 0, 0, 0);                                                                \
        acc0 = __builtin_amdgcn_mfma_f32_16x16x32_bf16(A4,                                 \
            *reinterpret_cast<const bf16x8*>(Bw + ((((BASE) + 4) * 64 + kbyte) ^ bswz)),   \
            acc0, 0, 0, 0);                                                                \
        acc1 = __builtin_amdgcn_mfma_f32_16x16x32_bf16(A5,                                 \
            *reinterpret_cast<const bf16x8*>(Bw + ((((BASE) + 5) * 64 + kbyte) ^ bswz)),   \
            acc1, 0, 0, 0);                                                                \
        acc2 = __builtin_amdgcn_mfma_f32_16x16x32_bf16(A6,                                 \
            *reinterpret_cast<const bf16x8*>(Bw + ((((BASE) + 6) * 64 + kbyte) ^ bswz)),   \
            acc2, 0, 0, 0);                                                                \
        acc3 = __builtin_amdgcn_mfma_f32_16x16x32_bf16(A7,                                 \
            *reinterpret_cast<const bf16x8*>(Bw + ((((BASE) + 7) * 64 + kbyte) ^ bswz)),   \
            acc3, 0, 0, 0);                                                                \
    } while (0)

// One 16x16 tile over K=1024: all 32 A-loads issued upfront, drained incrementally
// (vmcnt 24/16/8/0) -> one exposed L3 latency per phase.
__device__ __forceinline__ f32x4 phase_mm(const char* Ab, const char* Bw,
                                          int kbyte, int bswz)
{
    f32x4 acc0 = {0.f, 0.f, 0.f, 0.f}, acc1 = acc0, acc2 = acc0, acc3 = acc0;
    bf16x8 a0, a1, a2, a3, a4, a5, a6, a7;
    bf16x8 b0, b1, b2, b3, b4, b5, b6, b7;
    bf16x8 e0, e1, e2, e3, e4, e5, e6, e7;
    bf16x8 d0, d1, d2, d3, d4, d5, d6, d7;

    issue8(Ab,        a0, a1, a2, a3, a4, a5, a6, a7);
    issue8(Ab +  512, b0, b1, b2, b3, b4, b5, b6, b7);
    issue8(Ab + 1024, e0, e1, e2, e3, e4, e5, e6, e7);
    issue8(Ab + 1536, d0, d1, d2, d3, d4, d5, d6, d7);
    WAITN(24); MFMA8(0,  a0, a1, a2, a3, a4, a5, a6, a7);
    WAITN(16); MFMA8(8,  b0, b1, b2, b3, b4, b5, b6, b7);
    WAITN(8);  MFMA8(16, e0, e1, e2, e3, e4, e5, e6, e7);
    WAITN(0);  MFMA8(24, d0, d1, d2, d3, d4, d5, d6, d7);

    return (acc0 + acc1) + (acc2 + acc3);
}

extern "C" __global__ void __launch_bounds__(256, 1)
resrnn_kernel(const float* __restrict__ x,  const float* __restrict__ W1,
              const float* __restrict__ b1, const float* __restrict__ W2,
              const float* __restrict__ b2,
              __bf16* sBuf, __bf16* hBuf, float* sf32, unsigned* flags,
              float* __restrict__ dout)
{
    extern __shared__ char smem[];
    char*  W1s = smem;             // 64 KiB: [32 cols][1024 k] bf16, swizzled
    char*  W2s = smem + 65536;     // 64 KiB
    float* T   = (float*)(smem + 131072);  // 32 x TSTR f32 transpose scratch (4.5 KiB)

    const int tid = threadIdx.x;
    const int bid = blockIdx.x;
    const int g   = bid & 7;      // row group
    const int c   = bid >> 3;     // col block
    const int rb  = g * RPG;
    const int cb  = c * CPB;

    // ---- stage weight slices to LDS (fp32 -> bf16, XOR-swizzle by col) ----
    {
        const int lcw = tid >> 3;
        const int seg = (tid & 7) * 128;
        const int sw  = (lcw & 7) << 4;
        const float* w1p = W1 + (size_t)(cb + lcw) * SSZ + seg;
        const float* w2p = W2 + (size_t)(cb + lcw) * SSZ + seg;
        char* d1 = W1s + lcw * 2048;
        char* d2 = W2s + lcw * 2048;
        #pragma unroll 4
        for (int kk = 0; kk < 16; ++kk) {
            const int kb = (seg + kk * 8) * 2;
            f32x4 f0 = reinterpret_cast<const f32x4*>(w1p)[kk * 2 + 0];
            f32x4 f1 = reinterpret_cast<const f32x4*>(w1p)[kk * 2 + 1];
            bf16x8 v;
            v[0] = (__bf16)f0[0]; v[1] = (__bf16)f0[1]; v[2] = (__bf16)f0[2]; v[3] = (__bf16)f0[3];
            v[4] = (__bf16)f1[0]; v[5] = (__bf16)f1[1]; v[6] = (__bf16)f1[2]; v[7] = (__bf16)f1[3];
            *reinterpret_cast<bf16x8*>(d1 + (kb ^ sw)) = v;
            f0 = reinterpret_cast<const f32x4*>(w2p)[kk * 2 + 0];
            f1 = reinterpret_cast<const f32x4*>(w2p)[kk * 2 + 1];
            v[0] = (__bf16)f0[0]; v[1] = (__bf16)f0[1]; v[2] = (__bf16)f0[2]; v[3] = (__bf16)f0[3];
            v[4] = (__bf16)f1[0]; v[5] = (__bf16)f1[1]; v[6] = (__bf16)f1[2]; v[7] = (__bf16)f1[3];
            *reinterpret_cast<bf16x8*>(d2 + (kb ^ sw)) = v;
        }
    }

    // ---- init: sBuf = [x_0 | 0] (bf16), sf32[buf0] = 0, coherent stores (once) ----
    {
        const int e0  = tid * 4;
        const int row = rb + (e0 >> 5);
        const int col = cb + (e0 & 31);
        float* sp32 = sf32 + (size_t)row * SSZ + col;
        st_coh_f32(sp32 + 0, 0.f); st_coh_f32(sp32 + 1, 0.f);
        st_coh_f32(sp32 + 2, 0.f); st_coh_f32(sp32 + 3, 0.f);
        __bf16* sp = sBuf + (size_t)row * SSZ + col;
        if (c < 2) {
            const float* xp = x + (size_t)row * INSZ + col;
            #pragma unroll
            for (int i = 0; i < 4; ++i)
                st_coh_u16(sp + i, __builtin_bit_cast(unsigned short, (__bf16)xp[i]));
        } else {
            #pragma unroll
            for (int i = 0; i < 4; ++i)
                st_coh_u16(sp + i, __builtin_bit_cast(unsigned short, (__bf16)0.f));
        }
    }

    group_barrier(flags, g, c, 1u, tid);

    // ---- per-thread geometry (MFMA roles) ----
    const int lane  = tid & 63;
    const int wv    = tid >> 6;
    const int mh    = wv >> 1;                       // row half
    const int nh    = wv & 1;                        // col half
    const int kgrp  = lane >> 4;
    const int kbyte = kgrp * 16;
    const int arow  = rb + mh * 16 + (lane & 15);    // A operand row (global)
    const char* AbS = (const char*)sBuf + (size_t)arow * 2048 + kgrp * 16;
    const char* AbH = (const char*)hBuf + (size_t)arow * 2048 + kgrp * 16;
    const int lc    = nh * 16 + (lane & 15);         // local col 0..31
    const int bswz  = (lc & 7) << 4;
    const char* Bw1 = W1s + lc * 2048;
    const char* Bw2 = W2s + lc * 2048;
    const float bias1 = b1[cb + lc];
    const float bias2 = b2[cb + lc];
    const int lrow0 = mh * 16 + kgrp * 4;            // local C/D row base
    const int drow0 = rb + lrow0;                    // global C/D row base
    const int dcol  = cb + lc;                       // global C/D col
    const float P = 0.97f, OMP = 1.0f - 0.97f;

    // store-pass roles: thread covers row srow (0..31), 4 cols starting scol
    const int srow = tid >> 3;
    const int scol = (tid & 7) * 4;

    for (int t = 0; t < NSTEP; ++t) {
        // ---- phase 1: h = |s @ W1^T + b1| ----
        {
            f32x4 h4 = phase_mm(AbS, Bw1, kbyte, bswz);
            #pragma unroll
            for (int j = 0; j < 4; ++j)
                T[(lrow0 + j) * TSTR + lc] = fabsf(h4[j] + bias1);
        }
        __syncthreads();
        {   // full-line h publish: 8B bf16 per thread, 64B lines per 8 threads
            f32x4 hv = *reinterpret_cast<const f32x4*>(&T[srow * TSTR + scol]);
            st_coh_b64(hBuf + (size_t)(rb + srow) * SSZ + cb + scol, pack_bf16x4(hv));
        }

        // ---- prefetch sprev (residual input); latency hides under the barrier ----
        const float* srd = sf32 + (size_t)(t & 1) * (BATCH * SSZ);
        float sp0, sp1, sp2, sp3;
        if (c < 2) {  // shifted-in x_t columns: exact fp32 from read-only input
            const float* xp = x + (size_t)t * (BATCH * INSZ);
            sp0 = xp[(size_t)(drow0 + 0) * INSZ + dcol];
            sp1 = xp[(size_t)(drow0 + 1) * INSZ + dcol];
            sp2 = xp[(size_t)(drow0 + 2) * INSZ + dcol];
            sp3 = xp[(size_t)(drow0 + 3) * INSZ + dcol];
        } else {      // S(t) chunk written by WG(g,c-2) last step (synced since B2(t-1))
            issue4f(&srd[(size_t)(drow0 + 0) * SSZ + (dcol - 64)],
                    &srd[(size_t)(drow0 + 1) * SSZ + (dcol - 64)],
                    &srd[(size_t)(drow0 + 2) * SSZ + (dcol - 64)],
                    &srd[(size_t)(drow0 + 3) * SSZ + (dcol - 64)],
                    sp0, sp1, sp2, sp3);    // completed by barrier-entry vmcnt(0)
        }

        group_barrier(flags, g, c, (unsigned)(2 + 2 * t), tid);

        // ---- phase 2: S' = p*s + (1-p)*(h @ W2^T + b2) ----
        {
            f32x4 u4 = phase_mm(AbH, Bw2, kbyte, bswz);
            const float spv[4] = {sp0, sp1, sp2, sp3};
            #pragma unroll
            for (int j = 0; j < 4; ++j)
                T[(lrow0 + j) * TSTR + lc] = P * spv[j] + OMP * (u4[j] + bias2);
        }
        __syncthreads();
        {   // full-line publish of S(t+1): 16B f32 + 8B shifted bf16 per thread
            float* swr = sf32 + (size_t)((t + 1) & 1) * (BATCH * SSZ);
            f32x4 sv  = *reinterpret_cast<const f32x4*>(&T[srow * TSTR + scol]);
            const int grow = rb + srow;
            st_coh_b128(&swr[(size_t)grow * SSZ + cb + scol], sv);
            if (c < 30) {
                st_coh_b64(sBuf + (size_t)grow * SSZ + (cb + 64) + scol, pack_bf16x4(sv));
            } else if (t == NSTEP - 1) {
                *reinterpret_cast<f32x4*>(&dout[grow * 64 + (cb - 960) + scol]) = sv;
            }
            if (c < 2 && t < NSTEP - 1) {  // s_in(t+1) cols 0..63 = x_{t+1}
                f32x4 xv = *reinterpret_cast<const f32x4*>(
                    &x[(size_t)(t + 1) * (BATCH * INSZ) + (size_t)grow * INSZ + cb + scol]);
                st_coh_b64(sBuf + (size_t)grow * SSZ + cb + scol, pack_bf16x4(xv));
            }
        }
        if (t < NSTEP - 1)
            group_barrier(flags, g, c, (unsigned)(3 + 2 * t), tid);
    }
}

extern "C" void kernel_launch(void* const* d_in, const int* in_sizes, int n_in,
                              void* d_out, int out_size, void* d_ws, size_t ws_size,
                              hipStream_t stream)
{
    const float* x  = (const float*)d_in[0];
    const float* W1 = (const float*)d_in[1];
    const float* b1 = (const float*)d_in[2];
    const float* W2 = (const float*)d_in[3];
    const float* b2 = (const float*)d_in[4];
    float* dout = (float*)d_out;

    char* ws = (char*)d_ws;
    __bf16*   sBuf  = (__bf16*)(ws);                 // 512 KiB: shifted s_t, bf16
    __bf16*   hBuf  = (__bf16*)(ws + (512 << 10));   // 512 KiB: h, bf16
    float*    sf32  = (float*)(ws + (1 << 20));      // 2 MiB: fp32 S ping-pong
    unsigned* flags = (unsigned*)(ws + (3 << 20));   // 16 KiB: padded flags

    (void)in_sizes; (void)n_in; (void)out_size; (void)ws_size;

    (void)hipFuncSetAttribute(reinterpret_cast<const void*>(&resrnn_kernel),
                              hipFuncAttributeMaxDynamicSharedMemorySize, 135680);
    hipLaunchKernelGGL(resrnn_kernel, dim3(256), dim3(256), 135680, stream,
                       x, W1, b1, W2, b2, sBuf, hBuf, sf32, flags, dout);
}